// Round 1
// baseline (87843.005 us; speedup 1.0000x reference)
//
#include <hip/hip_runtime.h>
#include <hip/hip_bf16.h>
#include <math.h>

// Problem dims (fixed)
#define BATCH 128
#define LENC  1024
#define KVD   256
#define EMB   256
#define HID   512
#define VOC   1000
#define MH    1024
#define TSTEP 256
#define G4    2048   // 4*HID

__device__ __forceinline__ float sigm(float x) { return 1.f / (1.f + expf(-x)); }

// ---------------------------------------------------------------------------
// LSTM step: gates = [x(512) | h(512)] @ [Wih|Whh]^T + b, then cell update.
// grid = 256 blocks (64 h-tiles x 4 b-tiles), 512 threads (K split in 2).
// Tile: 32 gate-rows (8 h x 4 gates) x 32 batch.
// ---------------------------------------------------------------------------
__global__ __launch_bounds__(512) void lstm_step(
    int layer0,
    const float* __restrict__ x,        // layer>=1: [128][512] (lower layer h)
    const int*   __restrict__ labels,   // [128][256]
    int t,
    const int*   __restrict__ sos,      // device ptr, 1 int
    const float* __restrict__ embW,     // [1000][256]
    const float* __restrict__ ctx,      // [128][256] (ctxs slot t)
    const float* __restrict__ h_in,     // [128][512]
    const float* __restrict__ c_in,
    const float* __restrict__ Wih,      // [2048][512]
    const float* __restrict__ Whh,      // [2048][512]
    const float* __restrict__ bias,     // [2048]
    float* __restrict__ h_out,
    float* __restrict__ c_out)
{
    __shared__ __align__(16) float wsT[2][32][40]; // [khalf][kk][gate-row]
    __shared__ float xsh[2][32][33];               // [khalf][b][kk]
    __shared__ float gbuf[2][32][33];              // [khalf][gate-row][b]

    int tid = threadIdx.x;
    int kg  = tid >> 8;        // which K half
    int lt  = tid & 255;
    int h0  = (blockIdx.x >> 2) * 8;
    int bb  = (blockIdx.x & 3) * 32;
    int rgrp = lt >> 5;        // 0..7 -> rows rgrp*4..+3
    int bcol = lt & 31;

    float acc0 = 0.f, acc1 = 0.f, acc2 = 0.f, acc3 = 0.f;

    int kbase = kg * 512;
    for (int kc = kbase; kc < kbase + 512; kc += 32) {
        // --- load W tile: 32 gate-rows x 32 k ---
        #pragma unroll
        for (int i = 0; i < 4; ++i) {
            int idx = lt + 256 * i;
            int r = idx >> 5, kk = idx & 31;
            int wrow = ((r >> 3) << 9) + h0 + (r & 7);  // gate*512 + h index
            int k = kc + kk;
            float wv = (k < 512) ? Wih[(size_t)wrow * 512 + k]
                                 : Whh[(size_t)wrow * 512 + (k - 512)];
            wsT[kg][kk][r] = wv;
        }
        // --- load X tile: 32 b x 32 k  (x = [emb|ctx] or h_lower, then h_in) ---
        #pragma unroll
        for (int i = 0; i < 4; ++i) {
            int idx = lt + 256 * i;
            int bl = idx >> 5, kk = idx & 31;
            int b = bb + bl;
            int k = kc + kk;
            float xv;
            if (k >= 512) {
                xv = h_in[(size_t)b * 512 + (k - 512)];
            } else if (layer0) {
                if (k < 256) {
                    int lab = (t == 0) ? sos[0] : labels[b * 256 + (t - 1)];
                    xv = embW[(size_t)lab * 256 + k];
                } else {
                    xv = ctx[b * 256 + (k - 256)];
                }
            } else {
                xv = x[(size_t)b * 512 + k];
            }
            xsh[kg][bl][kk] = xv;
        }
        __syncthreads();
        #pragma unroll
        for (int kk = 0; kk < 32; ++kk) {
            float4 w4 = *(const float4*)&wsT[kg][kk][rgrp * 4];
            float xv = xsh[kg][bcol][kk];
            acc0 += w4.x * xv; acc1 += w4.y * xv;
            acc2 += w4.z * xv; acc3 += w4.w * xv;
        }
        __syncthreads();
    }

    gbuf[kg][rgrp * 4 + 0][bcol] = acc0;
    gbuf[kg][rgrp * 4 + 1][bcol] = acc1;
    gbuf[kg][rgrp * 4 + 2][bcol] = acc2;
    gbuf[kg][rgrp * 4 + 3][bcol] = acc3;
    __syncthreads();

    if (tid < 256) {
        int hl = rgrp, bl = bcol;
        int b = bb + bl, h = h0 + hl;
        float iv = gbuf[0][hl][bl]      + gbuf[1][hl][bl]      + bias[h];
        float fv = gbuf[0][8 + hl][bl]  + gbuf[1][8 + hl][bl]  + bias[512 + h];
        float gv = gbuf[0][16 + hl][bl] + gbuf[1][16 + hl][bl] + bias[1024 + h];
        float ov = gbuf[0][24 + hl][bl] + gbuf[1][24 + hl][bl] + bias[1536 + h];
        float co = c_in[(size_t)b * 512 + h];
        float cn = sigm(fv) * co + sigm(iv) * tanhf(gv);
        float hn = sigm(ov) * tanhf(cn);
        h_out[(size_t)b * 512 + h] = hn;
        c_out[(size_t)b * 512 + h] = cn;
    }
}

// ---------------------------------------------------------------------------
// Attention step: query = h2 @ fcW^T + fcb; energy = key . q; att = softmax(e*mask);
// ctx = att . value. One block per batch row, 1024 threads.
// ---------------------------------------------------------------------------
__global__ __launch_bounds__(1024) void attn_step(
    const float* __restrict__ h2,       // [128][512]
    const float* __restrict__ key,      // [128][1024][256]
    const float* __restrict__ value,    // [128][1024][256]
    const int*   __restrict__ seqlens,  // [128]
    const float* __restrict__ fcW,      // [256][512]
    const float* __restrict__ fcb,      // [256]
    float* __restrict__ q_out,          // q_all slice t: [128][256]
    float* __restrict__ ctx_out,        // ctxs slot t+1: [128][256]
    float* __restrict__ att_out,        // d_out attention base (B,L,T)
    int t)
{
    int b = blockIdx.x;
    int tid = threadIdx.x;
    __shared__ float h2s[512];
    __shared__ float q[256];
    __shared__ float red[1024];
    __shared__ float attsh[1024];

    if (tid < 512) h2s[tid] = h2[(size_t)b * 512 + tid];
    __syncthreads();

    {   // query: 4 threads per output k, 128-K partials, shuffle reduce
        int k = tid >> 2, part = tid & 3;
        const float* w  = fcW + (size_t)k * 512 + part * 128;
        const float* hh = h2s + part * 128;
        float s = 0.f;
        #pragma unroll 4
        for (int i = 0; i < 128; ++i) s += w[i] * hh[i];
        s += __shfl_xor(s, 1);
        s += __shfl_xor(s, 2);
        if (part == 0) q[k] = s + fcb[k];
    }
    __syncthreads();

    // energy for l = tid
    float e = 0.f;
    {
        const float* krow = key + ((size_t)b * LENC + tid) * KVD;
        #pragma unroll 4
        for (int k4 = 0; k4 < KVD; k4 += 4) {
            float4 kv = *(const float4*)(krow + k4);
            e += kv.x * q[k4] + kv.y * q[k4 + 1] + kv.z * q[k4 + 2] + kv.w * q[k4 + 3];
        }
    }
    int sl = seqlens[b];
    if (tid >= sl) e = 0.f;   // energy * mask (multiplicative mask!)

    // block max
    red[tid] = e; __syncthreads();
    for (int s = 512; s > 0; s >>= 1) {
        if (tid < s) red[tid] = fmaxf(red[tid], red[tid + s]);
        __syncthreads();
    }
    float m = red[0]; __syncthreads();
    float ex = expf(e - m);
    red[tid] = ex; __syncthreads();
    for (int s = 512; s > 0; s >>= 1) {
        if (tid < s) red[tid] += red[tid + s];
        __syncthreads();
    }
    float Z = red[0]; __syncthreads();
    float a = ex / Z;
    attsh[tid] = a;
    att_out[((size_t)b * LENC + tid) * TSTEP + t] = a;
    if (tid < 256) q_out[b * 256 + tid] = q[tid];
    __syncthreads();

    // ctx[k] = sum_l att[l]*value[b][l][k]
    {
        int k = tid & 255, g = tid >> 8;
        float s = 0.f;
        for (int l = g; l < LENC; l += 4)
            s += attsh[l] * value[((size_t)b * LENC + l) * KVD + k];
        red[tid] = s; __syncthreads();
        if (tid < 256)
            ctx_out[b * 256 + tid] = red[tid] + red[256 + tid] + red[512 + tid] + red[768 + tid];
    }
}

// ---------------------------------------------------------------------------
// Generic C = act(A @ B^T + bias). Tile 64x64, BK=16, 256 threads, 4x4/thread.
// amode: 0 plain A (lda=K); 1 gather rows from q_all/ctxs ([q|ctx] concat)
// cmode: 0 plain C (ldc=N); 1 scatter rows into y_hat (B,T,V)
// ---------------------------------------------------------------------------
__global__ __launch_bounds__(256) void gemm_bt(
    int amode, int act, int cmode, int t0,
    const float* __restrict__ A, const float* __restrict__ qall,
    const float* __restrict__ ctxs,
    const float* __restrict__ B, const float* __restrict__ bias,
    float* __restrict__ C,
    int M, int N, int K, int gridN)
{
    __shared__ float As[64][17];
    __shared__ float Bs[64][17];
    int bn = blockIdx.x % gridN;
    int bm = blockIdx.x / gridN;
    int m0 = bm * 64, n0 = bn * 64;
    int tid = threadIdx.x;
    int tx = tid & 15, ty = tid >> 4;
    int am = tid >> 2;            // 0..63 row within tile
    int ak = (tid & 3) * 4;       // 0,4,8,12
    float acc[4][4] = {};

    for (int k0 = 0; k0 < K; k0 += 16) {
        int gm = m0 + am;
        #pragma unroll
        for (int i = 0; i < 4; ++i) {
            int k = k0 + ak + i;
            float v;
            if (amode == 0) {
                v = A[(size_t)gm * K + k];
            } else {
                int tt = t0 + (gm >> 7), bb2 = gm & 127;
                v = (k < 256) ? qall[((size_t)tt * 128 + bb2) * 256 + k]
                              : ctxs[((size_t)(tt + 1) * 128 + bb2) * 256 + (k - 256)];
            }
            As[am][ak + i] = v;
        }
        int gn = n0 + am;
        #pragma unroll
        for (int i = 0; i < 4; ++i) {
            int k = k0 + ak + i;
            Bs[am][ak + i] = (gn < N) ? B[(size_t)gn * K + k] : 0.f;
        }
        __syncthreads();
        #pragma unroll
        for (int kk = 0; kk < 16; ++kk) {
            float a0 = As[ty * 4 + 0][kk], a1 = As[ty * 4 + 1][kk];
            float a2 = As[ty * 4 + 2][kk], a3 = As[ty * 4 + 3][kk];
            float b0 = Bs[tx * 4 + 0][kk], b1 = Bs[tx * 4 + 1][kk];
            float b2 = Bs[tx * 4 + 2][kk], b3 = Bs[tx * 4 + 3][kk];
            acc[0][0] += a0 * b0; acc[0][1] += a0 * b1; acc[0][2] += a0 * b2; acc[0][3] += a0 * b3;
            acc[1][0] += a1 * b0; acc[1][1] += a1 * b1; acc[1][2] += a1 * b2; acc[1][3] += a1 * b3;
            acc[2][0] += a2 * b0; acc[2][1] += a2 * b1; acc[2][2] += a2 * b2; acc[2][3] += a2 * b3;
            acc[3][0] += a3 * b0; acc[3][1] += a3 * b1; acc[3][2] += a3 * b2; acc[3][3] += a3 * b3;
        }
        __syncthreads();
    }

    #pragma unroll
    for (int i = 0; i < 4; ++i) {
        int gm = m0 + ty * 4 + i;
        int tt = 0, bb2 = 0;
        if (cmode == 1) { tt = t0 + (gm >> 7); bb2 = gm & 127; }
        #pragma unroll
        for (int j = 0; j < 4; ++j) {
            int gn = n0 + tx * 4 + j;
            if (gn >= N) continue;
            float v = acc[i][j] + bias[gn];
            if (act == 1) v = (v >= 0.f) ? v : 0.9f * v;
            if (cmode == 0) C[(size_t)gm * N + gn] = v;
            else C[((size_t)bb2 * TSTEP + tt) * VOC + gn] = v;
        }
    }
}

// ---------------------------------------------------------------------------
// Row argmax over V=1000 (first-max tiebreak, numpy semantics), label as float
// ---------------------------------------------------------------------------
__global__ __launch_bounds__(256) void argmax_k(
    const float* __restrict__ yhat, float* __restrict__ lab)
{
    int row = blockIdx.x;
    const float* p = yhat + (size_t)row * VOC;
    int tid = threadIdx.x;
    float bv = -1e30f; int bi = 0;
    for (int o = tid; o < VOC; o += 256) {
        float v = p[o];
        if (v > bv) { bv = v; bi = o; }  // ascending o -> first max kept
    }
    __shared__ float sv[256];
    __shared__ int   si[256];
    sv[tid] = bv; si[tid] = bi; __syncthreads();
    for (int s = 128; s > 0; s >>= 1) {
        if (tid < s) {
            float v2 = sv[tid + s]; int i2 = si[tid + s];
            if (v2 > sv[tid] || (v2 == sv[tid] && i2 < si[tid])) { sv[tid] = v2; si[tid] = i2; }
        }
        __syncthreads();
    }
    if (tid == 0) lab[row] = (float)si[0];
}

// ---------------------------------------------------------------------------

extern "C" void kernel_launch(void* const* d_in, const int* in_sizes, int n_in,
                              void* d_out, int out_size, void* d_ws, size_t ws_size,
                              hipStream_t stream) {
    const float* key      = (const float*)d_in[0];
    const float* value    = (const float*)d_in[1];
    const int*   labels   = (const int*)d_in[2];
    const int*   seqlens  = (const int*)d_in[3];
    const int*   sos      = (const int*)d_in[4];
    const float* embW     = (const float*)d_in[5];
    const float* l0_Wih   = (const float*)d_in[6];
    const float* l0_Whh   = (const float*)d_in[7];
    const float* l0_b     = (const float*)d_in[8];
    const float* lr_Wih   = (const float*)d_in[9];
    const float* lr_Whh   = (const float*)d_in[10];
    const float* lr_b     = (const float*)d_in[11];
    const float* fcW      = (const float*)d_in[12];
    const float* fcb      = (const float*)d_in[13];
    const float* mlp_W1   = (const float*)d_in[14];
    const float* mlp_b1   = (const float*)d_in[15];
    const float* mlp_W2   = (const float*)d_in[16];
    const float* mlp_b2   = (const float*)d_in[17];

    float* ws = (float*)d_ws;
    // ws layout (floats)
    const size_t OFF_QALL = 0;                               // T*B*256
    const size_t OFF_CTXS = OFF_QALL + (size_t)TSTEP * 32768; // (T+1)*B*256
    const size_t OFF_H    = OFF_CTXS + (size_t)(TSTEP + 1) * 32768; // 3*2*65536
    const size_t OFF_C    = OFF_H + 6 * 65536;
    const size_t OFF_Z1   = OFF_C + 6 * 65536;               // Tc*B*1024

    float* q_all = ws + OFF_QALL;
    float* ctxs  = ws + OFF_CTXS;
    float* z1    = ws + OFF_Z1;

    // pick MLP t-chunk size that fits ws
    int Tc = 64;
    while (Tc > 1 && (OFF_Z1 + (size_t)Tc * 131072) * 4 > ws_size) Tc >>= 1;

    // d_out layout: y_hat (B,T,V) | labels (B,T) | attentions (B,L,T)
    float* yhat = (float*)d_out;
    float* lab  = yhat + (size_t)BATCH * TSTEP * VOC;
    float* att  = lab + (size_t)BATCH * TSTEP;

    // zero-init h, c, ctx slot 0
    hipMemsetAsync(ws + OFF_H, 0, 6 * 65536 * sizeof(float), stream);
    hipMemsetAsync(ws + OFF_C, 0, 6 * 65536 * sizeof(float), stream);
    hipMemsetAsync(ctxs, 0, 32768 * sizeof(float), stream);

    auto HP = [&](int l, int p) { return ws + OFF_H + ((size_t)l * 2 + p) * 65536; };
    auto CP = [&](int l, int p) { return ws + OFF_C + ((size_t)l * 2 + p) * 65536; };

    for (int t = 0; t < TSTEP; ++t) {
        int p = t & 1, pn = p ^ 1;
        // layer 0
        lstm_step<<<256, 512, 0, stream>>>(
            1, nullptr, labels, t, sos, embW, ctxs + (size_t)t * 32768,
            HP(0, p), CP(0, p), l0_Wih, l0_Whh, l0_b, HP(0, pn), CP(0, pn));
        // layer 1
        lstm_step<<<256, 512, 0, stream>>>(
            0, HP(0, pn), labels, t, sos, embW, nullptr,
            HP(1, p), CP(1, p), lr_Wih, lr_Whh, lr_b, HP(1, pn), CP(1, pn));
        // layer 2
        lstm_step<<<256, 512, 0, stream>>>(
            0, HP(1, pn), labels, t, sos, embW, nullptr,
            HP(2, p), CP(2, p), lr_Wih + (size_t)G4 * 512, lr_Whh + (size_t)G4 * 512,
            lr_b + G4, HP(2, pn), CP(2, pn));
        // attention
        attn_step<<<BATCH, 1024, 0, stream>>>(
            HP(2, pn), key, value, seqlens, fcW, fcb,
            q_all + (size_t)t * 32768, ctxs + (size_t)(t + 1) * 32768, att, t);
    }

    // batched MLP head over all (t, b) rows, chunked in t
    int nch = TSTEP / Tc;
    for (int c = 0; c < nch; ++c) {
        int t0 = c * Tc;
        int M = Tc * BATCH;
        int gridM = M / 64;
        // z1 = leaky( [q|ctx] @ W1^T + b1 )
        gemm_bt<<<gridM * 16, 256, 0, stream>>>(
            1, 1, 0, t0, nullptr, q_all, ctxs, mlp_W1, mlp_b1, z1,
            M, MH, 512, 16);
        // logits = z1 @ W2^T + b2, scattered into y_hat
        gemm_bt<<<gridM * 16, 256, 0, stream>>>(
            0, 0, 1, t0, z1, nullptr, nullptr, mlp_W2, mlp_b2, yhat,
            M, VOC, MH, 16);
    }

    argmax_k<<<BATCH * TSTEP, 256, 0, stream>>>(yhat, lab);
}

// Round 3
// 43112.540 us; speedup vs baseline: 2.0375x; 2.0375x over previous
//
#include <hip/hip_runtime.h>
#include <hip/hip_bf16.h>
#include <math.h>

// Problem dims (fixed)
#define BATCH 128
#define LENC  1024
#define KVD   256
#define HID   512
#define VOC   1000
#define MH    1024
#define TSTEP 256

__device__ __forceinline__ float sigm(float x) { return 1.f / (1.f + expf(-x)); }

// ---------------------------------------------------------------------------
// LSTM gate GEMM, K-split by 8. part[s][b][g] = sum_{k in s-th 128-slice}
//   X[k][b] * Wcat[g][k], Wcat = [Wih | Whh] (K=1024), X = [x | h_rec].
// grid 512 = 32 g-tiles(64) x 2 b-tiles(64) x 8 K-slices. 256 thr, 4x4 acc.
// VALU-bound: 2 ds_read_b128 (24 cyc) per 16 FMA (32 cyc) per wave-iter.
// ---------------------------------------------------------------------------
template<int MODE>  // 0: cell0 (x = [emb|ctx]), 1: cells 1/2 (x = lower h)
__global__ __launch_bounds__(256) void lstm_gemm(
    const float* __restrict__ Wih,     // [2048][512]
    const float* __restrict__ Whh,     // [2048][512]
    const float* __restrict__ xA,      // MODE1: lower-layer h [128][512]
    const float* __restrict__ hR,      // recurrent h (prev step) [128][512]
    const float* __restrict__ embW,    // [1000][256]
    const int*   __restrict__ labels,  // [128][256]
    const int*   __restrict__ sos,
    const float* __restrict__ ctx,     // ctx_all slot t: [128][256]
    int t,
    float* __restrict__ part)          // [8][128][2048]
{
    __shared__ float WsT[32][69];   // [k][g] pad 69: staging writes 2-way max
    __shared__ float XsT[32][69];   // [k][b]

    int blk = blockIdx.x;
    int s  = blk & 7;
    int bt = (blk >> 3) & 1;
    int gt = blk >> 4;
    int tid = threadIdx.x;
    int r  = tid >> 2;          // 0..63: row within tile (g or b)
    int kq = (tid & 3) * 8;     // 0,8,16,24: k-subrange within 32-chunk

    int g = gt * 64 + r;
    const float* wbase = (s < 4) ? (Wih + (size_t)g * 512 + s * 128)
                                 : (Whh + (size_t)g * 512 + (s - 4) * 128);
    int b = bt * 64 + r;
    const float* xbase;
    if (MODE == 0) {
        if (s < 2) {
            int lab = (t == 0) ? sos[0] : labels[b * TSTEP + (t - 1)];
            xbase = embW + (size_t)lab * 256 + s * 128;
        } else if (s < 4) {
            xbase = ctx + (size_t)b * 256 + (s - 2) * 128;
        } else {
            xbase = hR + (size_t)b * 512 + (s - 4) * 128;
        }
    } else {
        xbase = (s < 4) ? (xA + (size_t)b * 512 + s * 128)
                        : (hR + (size_t)b * 512 + (s - 4) * 128);
    }

    int tg = tid >> 4, tb = tid & 15;
    float acc[4][4] = {};  // [j=b-dir][i=g-dir]

    for (int kc = 0; kc < 128; kc += 32) {
        float4 w0 = *(const float4*)(wbase + kc + kq);
        float4 w1 = *(const float4*)(wbase + kc + kq + 4);
        float4 x0 = *(const float4*)(xbase + kc + kq);
        float4 x1 = *(const float4*)(xbase + kc + kq + 4);
        WsT[kq + 0][r] = w0.x; WsT[kq + 1][r] = w0.y;
        WsT[kq + 2][r] = w0.z; WsT[kq + 3][r] = w0.w;
        WsT[kq + 4][r] = w1.x; WsT[kq + 5][r] = w1.y;
        WsT[kq + 6][r] = w1.z; WsT[kq + 7][r] = w1.w;
        XsT[kq + 0][r] = x0.x; XsT[kq + 1][r] = x0.y;
        XsT[kq + 2][r] = x0.z; XsT[kq + 3][r] = x0.w;
        XsT[kq + 4][r] = x1.x; XsT[kq + 5][r] = x1.y;
        XsT[kq + 6][r] = x1.z; XsT[kq + 7][r] = x1.w;
        __syncthreads();
        #pragma unroll
        for (int kk = 0; kk < 32; ++kk) {
            float4 wv = *(const float4*)&WsT[kk][tg * 4];
            float4 xv = *(const float4*)&XsT[kk][tb * 4];
            acc[0][0] += xv.x * wv.x; acc[0][1] += xv.x * wv.y;
            acc[0][2] += xv.x * wv.z; acc[0][3] += xv.x * wv.w;
            acc[1][0] += xv.y * wv.x; acc[1][1] += xv.y * wv.y;
            acc[1][2] += xv.y * wv.z; acc[1][3] += xv.y * wv.w;
            acc[2][0] += xv.z * wv.x; acc[2][1] += xv.z * wv.y;
            acc[2][2] += xv.z * wv.z; acc[2][3] += xv.z * wv.w;
            acc[3][0] += xv.w * wv.x; acc[3][1] += xv.w * wv.y;
            acc[3][2] += xv.w * wv.z; acc[3][3] += xv.w * wv.w;
        }
        __syncthreads();
    }

    size_t pb = ((size_t)s * 128 + bt * 64 + tb * 4) * 2048 + gt * 64 + tg * 4;
    #pragma unroll
    for (int j = 0; j < 4; ++j) {
        float4 o = { acc[j][0], acc[j][1], acc[j][2], acc[j][3] };
        *(float4*)&part[pb + (size_t)j * 2048] = o;
    }
}

// ---------------------------------------------------------------------------
// Gate combine for cells 0/1: sum 8 partials + bias, LSTM nonlinearities.
// grid 256 = (b, h-half), 256 thr. part layout [s][b][g] -> coalesced loads.
// ---------------------------------------------------------------------------
__global__ __launch_bounds__(256) void lstm_combine(
    const float* __restrict__ part, const float* __restrict__ bias,
    float* __restrict__ h, float* __restrict__ c)
{
    int b  = blockIdx.x >> 1;
    int hh = ((blockIdx.x & 1) << 8) + threadIdx.x;
    const float* pb = part + (size_t)b * 2048;
    float iv = bias[hh], fv = bias[512 + hh], gv = bias[1024 + hh], ov = bias[1536 + hh];
    #pragma unroll
    for (int s = 0; s < 8; ++s) {
        const float* p = pb + (size_t)s * 262144;
        iv += p[hh]; fv += p[512 + hh]; gv += p[1024 + hh]; ov += p[1536 + hh];
    }
    size_t idx = (size_t)b * 512 + hh;
    float cn = sigm(fv) * c[idx] + sigm(iv) * tanhf(gv);
    c[idx] = cn;
    h[idx] = sigm(ov) * tanhf(cn);
}

// ---------------------------------------------------------------------------
// Cell-2 combine fused with query: h2,c2 from part2, then q = fcW@h2 + fcb.
// grid 128 (one per b), 256 thr.
// ---------------------------------------------------------------------------
__global__ __launch_bounds__(256) void qk_kernel(
    const float* __restrict__ part, const float* __restrict__ bias,
    const float* __restrict__ fcW, const float* __restrict__ fcb,
    float* __restrict__ h2, float* __restrict__ c2,
    float* __restrict__ qout)               // q_all + t*32768
{
    __shared__ float h2s[512];
    int b = blockIdx.x;
    int tid = threadIdx.x;
    const float* pb = part + (size_t)b * 2048;
    #pragma unroll
    for (int e = 0; e < 2; ++e) {
        int hh = tid + e * 256;
        float iv = bias[hh], fv = bias[512 + hh], gv = bias[1024 + hh], ov = bias[1536 + hh];
        #pragma unroll
        for (int s = 0; s < 8; ++s) {
            const float* p = pb + (size_t)s * 262144;
            iv += p[hh]; fv += p[512 + hh]; gv += p[1024 + hh]; ov += p[1536 + hh];
        }
        size_t idx = (size_t)b * 512 + hh;
        float cn = sigm(fv) * c2[idx] + sigm(iv) * tanhf(gv);
        c2[idx] = cn;
        float hn = sigm(ov) * tanhf(cn);
        h2[idx] = hn;
        h2s[hh] = hn;
    }
    __syncthreads();
    const float* w = fcW + (size_t)tid * 512;
    float a0 = 0.f, a1 = 0.f;
    #pragma unroll 4
    for (int c0 = 0; c0 < 512; c0 += 2) {
        a0 += w[c0] * h2s[c0];
        a1 += w[c0 + 1] * h2s[c0 + 1];
    }
    qout[b * 256 + tid] = a0 + a1 + fcb[tid];
}

// ---------------------------------------------------------------------------
// Attention energies + per-quarter softmax stats.
// grid 512 = (b, L-quarter of 256). Wave-cooperative row dots: 64 lanes read
// one contiguous 1KB key row (coalesced), shfl_xor reduce.
// e_ws stores exp(e - m_local); stats = (m_local, sum).
// Mask is MULTIPLICATIVE (ref: softmax(energy*mask)): masked rows e = 0.
// ---------------------------------------------------------------------------
__global__ __launch_bounds__(256) void attn_e(
    const float* __restrict__ key, const int* __restrict__ seqlens,
    const float* __restrict__ qall,          // + t*32768
    float* __restrict__ e_ws,                // [128][1024]
    float* __restrict__ stats)               // [128][4][2]
{
    __shared__ float e_sh[256];
    __shared__ float sred[8];
    int b = blockIdx.x >> 2, qt = blockIdx.x & 3;
    int tid = threadIdx.x, lane = tid & 63, w = tid >> 6;

    float4 q4 = *(const float4*)(qall + (size_t)b * 256 + lane * 4);
    int sl = seqlens[b];
    int lbase = qt * 256 + w * 64;
    const float4* keyb = (const float4*)key + ((size_t)b * 1024 + lbase) * 64;

    #pragma unroll 4
    for (int i = 0; i < 64; ++i) {
        float4 kv = keyb[(size_t)i * 64 + lane];
        float e = kv.x * q4.x + kv.y * q4.y + kv.z * q4.z + kv.w * q4.w;
        e += __shfl_xor(e, 1);  e += __shfl_xor(e, 2);  e += __shfl_xor(e, 4);
        e += __shfl_xor(e, 8);  e += __shfl_xor(e, 16); e += __shfl_xor(e, 32);
        if (lane == i) e_sh[w * 64 + i] = (lbase + i < sl) ? e : 0.f;
    }
    __syncthreads();

    float x = e_sh[tid];
    float m = x;
    m = fmaxf(m, __shfl_xor(m, 1));  m = fmaxf(m, __shfl_xor(m, 2));
    m = fmaxf(m, __shfl_xor(m, 4));  m = fmaxf(m, __shfl_xor(m, 8));
    m = fmaxf(m, __shfl_xor(m, 16)); m = fmaxf(m, __shfl_xor(m, 32));
    if (lane == 0) sred[w] = m;
    __syncthreads();
    m = fmaxf(fmaxf(sred[0], sred[1]), fmaxf(sred[2], sred[3]));
    float p = expf(x - m);
    e_ws[(size_t)b * 1024 + qt * 256 + tid] = p;
    float ss = p;
    ss += __shfl_xor(ss, 1);  ss += __shfl_xor(ss, 2);  ss += __shfl_xor(ss, 4);
    ss += __shfl_xor(ss, 8);  ss += __shfl_xor(ss, 16); ss += __shfl_xor(ss, 32);
    if (lane == 0) sred[4 + w] = ss;
    __syncthreads();
    if (tid == 0) {
        float S = sred[4] + sred[5] + sred[6] + sred[7];
        stats[((size_t)b * 4 + qt) * 2]     = m;
        stats[((size_t)b * 4 + qt) * 2 + 1] = S;
    }
}

// ---------------------------------------------------------------------------
// Softmax finalize + context partial. grid 512 = (b, quarter), 256 thr.
// ctx combined across quarters via atomicAdd (slot memset once at start).
// ---------------------------------------------------------------------------
__global__ __launch_bounds__(256) void attn_c(
    const float* __restrict__ value, const float* __restrict__ e_ws,
    const float* __restrict__ stats,
    float* __restrict__ att_out,             // d_out att base (B,L,T)
    float* __restrict__ ctx_next,            // ctx_all + (t+1)*32768
    int t)
{
    __shared__ float att_sh[256];
    __shared__ __align__(16) float ctxr[4][256];
    int b = blockIdx.x >> 2, qt = blockIdx.x & 3;
    int tid = threadIdx.x;

    const float* st = stats + (size_t)b * 8;
    float m0 = st[0], S0 = st[1], m1 = st[2], S1 = st[3];
    float m2 = st[4], S2 = st[5], m3 = st[6], S3 = st[7];
    float m = fmaxf(fmaxf(m0, m1), fmaxf(m2, m3));
    float Z = S0 * expf(m0 - m) + S1 * expf(m1 - m)
            + S2 * expf(m2 - m) + S3 * expf(m3 - m);
    float scale = expf(st[qt * 2] - m) / Z;

    float a = e_ws[(size_t)b * 1024 + qt * 256 + tid] * scale;
    att_sh[tid] = a;
    att_out[((size_t)b * 1024 + qt * 256 + tid) * 256 + t] = a;
    __syncthreads();

    int kq = tid & 63, lg = tid >> 6;
    const float4* vb = (const float4*)value + ((size_t)b * 1024 + qt * 256 + lg * 64) * 64;
    float4 acc = { 0.f, 0.f, 0.f, 0.f };
    #pragma unroll 4
    for (int i = 0; i < 64; ++i) {
        float av = att_sh[lg * 64 + i];
        float4 v = vb[(size_t)i * 64 + kq];
        acc.x += av * v.x; acc.y += av * v.y;
        acc.z += av * v.z; acc.w += av * v.w;
    }
    *(float4*)&ctxr[lg][kq * 4] = acc;
    __syncthreads();
    float ssum = ctxr[0][tid] + ctxr[1][tid] + ctxr[2][tid] + ctxr[3][tid];
    atomicAdd(&ctx_next[(size_t)b * 256 + tid], ssum);
}

// ---------------------------------------------------------------------------
// Generic C = act(A @ B^T + bias). Tile 64x64, BK=16, 256 threads, 4x4/thread.
// amode: 0 plain A (lda=K); 1 gather rows as [q_all | ctx_all] concat
// cmode: 0 plain C; 1 scatter rows into y_hat (B,T,V)
// ---------------------------------------------------------------------------
__global__ __launch_bounds__(256) void gemm_bt(
    int amode, int act, int cmode, int t0,
    const float* __restrict__ A, const float* __restrict__ qall,
    const float* __restrict__ ctx_all,
    const float* __restrict__ B, const float* __restrict__ bias,
    float* __restrict__ C,
    int M, int N, int K, int gridN)
{
    __shared__ float As[64][17];
    __shared__ float Bs[64][17];
    int bn = blockIdx.x % gridN;
    int bm = blockIdx.x / gridN;
    int m0 = bm * 64, n0 = bn * 64;
    int tid = threadIdx.x;
    int tx = tid & 15, ty = tid >> 4;
    int am = tid >> 2;
    int ak = (tid & 3) * 4;
    float acc[4][4] = {};

    for (int k0 = 0; k0 < K; k0 += 16) {
        int gm = m0 + am;
        #pragma unroll
        for (int i = 0; i < 4; ++i) {
            int k = k0 + ak + i;
            float v;
            if (amode == 0) {
                v = A[(size_t)gm * K + k];
            } else {
                int tt = t0 + (gm >> 7), bb2 = gm & 127;
                v = (k < 256) ? qall[((size_t)tt * 128 + bb2) * 256 + k]
                              : ctx_all[((size_t)(tt + 1) * 128 + bb2) * 256 + (k - 256)];
            }
            As[am][ak + i] = v;
        }
        int gn = n0 + am;
        #pragma unroll
        for (int i = 0; i < 4; ++i) {
            int k = k0 + ak + i;
            Bs[am][ak + i] = (gn < N) ? B[(size_t)gn * K + k] : 0.f;
        }
        __syncthreads();
        #pragma unroll
        for (int kk = 0; kk < 16; ++kk) {
            float a0 = As[ty * 4 + 0][kk], a1 = As[ty * 4 + 1][kk];
            float a2 = As[ty * 4 + 2][kk], a3 = As[ty * 4 + 3][kk];
            float b0 = Bs[tx * 4 + 0][kk], b1 = Bs[tx * 4 + 1][kk];
            float b2 = Bs[tx * 4 + 2][kk], b3 = Bs[tx * 4 + 3][kk];
            acc[0][0] += a0 * b0; acc[0][1] += a0 * b1; acc[0][2] += a0 * b2; acc[0][3] += a0 * b3;
            acc[1][0] += a1 * b0; acc[1][1] += a1 * b1; acc[1][2] += a1 * b2; acc[1][3] += a1 * b3;
            acc[2][0] += a2 * b0; acc[2][1] += a2 * b1; acc[2][2] += a2 * b2; acc[2][3] += a2 * b3;
            acc[3][0] += a3 * b0; acc[3][1] += a3 * b1; acc[3][2] += a3 * b2; acc[3][3] += a3 * b3;
        }
        __syncthreads();
    }

    #pragma unroll
    for (int i = 0; i < 4; ++i) {
        int gm = m0 + ty * 4 + i;
        int tt = 0, bb2 = 0;
        if (cmode == 1) { tt = t0 + (gm >> 7); bb2 = gm & 127; }
        #pragma unroll
        for (int j = 0; j < 4; ++j) {
            int gn = n0 + tx * 4 + j;
            if (gn >= N) continue;
            float v = acc[i][j] + bias[gn];
            if (act == 1) v = (v >= 0.f) ? v : 0.9f * v;
            if (cmode == 0) C[(size_t)gm * N + gn] = v;
            else C[((size_t)bb2 * TSTEP + tt) * VOC + gn] = v;
        }
    }
}

// ---------------------------------------------------------------------------
// Row argmax over V=1000 (first-max tiebreak), label as float
// ---------------------------------------------------------------------------
__global__ __launch_bounds__(256) void argmax_k(
    const float* __restrict__ yhat, float* __restrict__ lab)
{
    int row = blockIdx.x;
    const float* p = yhat + (size_t)row * VOC;
    int tid = threadIdx.x;
    float bv = -1e30f; int bi = 0;
    for (int o = tid; o < VOC; o += 256) {
        float v = p[o];
        if (v > bv) { bv = v; bi = o; }
    }
    __shared__ float sv[256];
    __shared__ int   si[256];
    sv[tid] = bv; si[tid] = bi; __syncthreads();
    for (int s = 128; s > 0; s >>= 1) {
        if (tid < s) {
            float v2 = sv[tid + s]; int i2 = si[tid + s];
            if (v2 > sv[tid] || (v2 == sv[tid] && i2 < si[tid])) { sv[tid] = v2; si[tid] = i2; }
        }
        __syncthreads();
    }
    if (tid == 0) lab[row] = (float)si[0];
}

// ---------------------------------------------------------------------------

extern "C" void kernel_launch(void* const* d_in, const int* in_sizes, int n_in,
                              void* d_out, int out_size, void* d_ws, size_t ws_size,
                              hipStream_t stream) {
    const float* key     = (const float*)d_in[0];
    const float* value   = (const float*)d_in[1];
    const int*   labels  = (const int*)d_in[2];
    const int*   seqlens = (const int*)d_in[3];
    const int*   sos     = (const int*)d_in[4];
    const float* embW    = (const float*)d_in[5];
    const float* l0_Wih  = (const float*)d_in[6];
    const float* l0_Whh  = (const float*)d_in[7];
    const float* l0_b    = (const float*)d_in[8];
    const float* lr_Wih  = (const float*)d_in[9];
    const float* lr_Whh  = (const float*)d_in[10];
    const float* lr_b    = (const float*)d_in[11];
    const float* fcW     = (const float*)d_in[12];
    const float* fcb     = (const float*)d_in[13];
    const float* mlp_W1  = (const float*)d_in[14];
    const float* mlp_b1  = (const float*)d_in[15];
    const float* mlp_W2  = (const float*)d_in[16];
    const float* mlp_b2  = (const float*)d_in[17];

    float* ws = (float*)d_ws;
    // ws layout (floats)
    const size_t OFF_QALL = 0;                          // 256*128*256
    const size_t OFF_CTX  = OFF_QALL + 8388608;         // 257*128*256
    const size_t OFF_PART = OFF_CTX + 8421376;          // 8*128*2048
    const size_t OFF_H    = OFF_PART + 2097152;         // 3*65536
    const size_t OFF_C    = OFF_H + 196608;             // 3*65536
    const size_t OFF_EW   = OFF_C + 196608;             // 128*1024
    const size_t OFF_ST   = OFF_EW + 131072;            // 1024
    const size_t OFF_Z1   = OFF_ST + 1024;              // Tc*128*1024

    float* q_all   = ws + OFF_QALL;
    float* ctx_all = ws + OFF_CTX;
    float* part    = ws + OFF_PART;
    float* h0 = ws + OFF_H;           float* h1 = h0 + 65536; float* h2 = h1 + 65536;
    float* c0 = ws + OFF_C;           float* c1 = c0 + 65536; float* c2 = c1 + 65536;
    float* e_ws  = ws + OFF_EW;
    float* stats = ws + OFF_ST;
    float* z1    = ws + OFF_Z1;

    int Tc = 32;
    while (Tc > 1 && (OFF_Z1 + (size_t)Tc * 131072) * 4 > ws_size) Tc >>= 1;

    // d_out layout: y_hat (B,T,V) | labels (B,T) | attentions (B,L,T)
    float* yhat = (float*)d_out;
    float* lab  = yhat + (size_t)BATCH * TSTEP * VOC;
    float* att  = lab + (size_t)BATCH * TSTEP;

    // zero-init h/c and ctx_all (ws is re-poisoned before every launch)
    hipMemsetAsync(ws + OFF_H, 0, 393216 * sizeof(float), stream);
    hipMemsetAsync(ctx_all, 0, 8421376 * sizeof(float), stream);

    const float* l2_Wih = lr_Wih + (size_t)2048 * 512;
    const float* l2_Whh = lr_Whh + (size_t)2048 * 512;
    const float* l2_b   = lr_b + 2048;

    for (int t = 0; t < TSTEP; ++t) {
        const float* ctx_t = ctx_all + (size_t)t * 32768;
        lstm_gemm<0><<<512, 256, 0, stream>>>(
            l0_Wih, l0_Whh, nullptr, h0, embW, labels, sos, ctx_t, t, part);
        lstm_combine<<<256, 256, 0, stream>>>(part, l0_b, h0, c0);
        lstm_gemm<1><<<512, 256, 0, stream>>>(
            lr_Wih, lr_Whh, h0, h1, embW, labels, sos, ctx_t, t, part);
        lstm_combine<<<256, 256, 0, stream>>>(part, lr_b, h1, c1);
        lstm_gemm<1><<<512, 256, 0, stream>>>(
            l2_Wih, l2_Whh, h1, h2, embW, labels, sos, ctx_t, t, part);
        qk_kernel<<<128, 256, 0, stream>>>(
            part, l2_b, fcW, fcb, h2, c2, q_all + (size_t)t * 32768);
        attn_e<<<512, 256, 0, stream>>>(
            key, seqlens, q_all + (size_t)t * 32768, e_ws, stats);
        attn_c<<<512, 256, 0, stream>>>(
            value, e_ws, stats, att, ctx_all + (size_t)(t + 1) * 32768, t);
    }

    // batched MLP head over all (t, b) rows, chunked in t
    int nch = TSTEP / Tc;
    for (int cix = 0; cix < nch; ++cix) {
        int t0 = cix * Tc;
        int M = Tc * BATCH;
        int gridM = M / 64;
        gemm_bt<<<gridM * 16, 256, 0, stream>>>(
            1, 1, 0, t0, nullptr, q_all, ctx_all, mlp_W1, mlp_b1, z1,
            M, MH, 512, 16);
        gemm_bt<<<gridM * 16, 256, 0, stream>>>(
            0, 0, 1, t0, z1, nullptr, nullptr, mlp_W2, mlp_b2, yhat,
            M, VOC, MH, 16);
    }

    argmax_k<<<BATCH * TSTEP, 256, 0, stream>>>(yhat, lab);
}